// Round 1
// baseline (2041.758 us; speedup 1.0000x reference)
//
#include <hip/hip_runtime.h>
#include <hip/hip_bf16.h>
#include <math.h>

#define B_   1024
#define ZD_  256
#define HD_  1024
#define L_   32
#define NW_  64
#define XD_  1024
#define KA_  1280   // concat K: 1024 (h) + 256 (z)
#define THD_ 3072
#define NB_  4096   // augmented N: r, u, hn, xn

typedef __attribute__((ext_vector_type(8))) short short8;
typedef __attribute__((ext_vector_type(4))) float f32x4;

__device__ __forceinline__ unsigned short f2bf(float f) {
  unsigned int u = __float_as_uint(f);
  u += 0x7fffu + ((u >> 16) & 1u);   // RNE
  return (unsigned short)(u >> 16);
}
__device__ __forceinline__ float sig_(float x) { return 1.0f / (1.0f + __expf(-x)); }
__device__ __forceinline__ float tanh_(float x) {
  float e = __expf(2.0f * x);
  return 1.0f - 2.0f / (e + 1.0f);
}
__device__ __forceinline__ f32x4 mfma16(short8 a, short8 b, f32x4 c) {
  return __builtin_amdgcn_mfma_f32_16x16x32_bf16(a, b, c, 0, 0, 0);
}
__device__ __forceinline__ short8 pack8(f32x4 f0, f32x4 f1) {
  short8 v;
  v[0] = (short)f2bf(f0[0]); v[1] = (short)f2bf(f0[1]);
  v[2] = (short)f2bf(f0[2]); v[3] = (short)f2bf(f0[3]);
  v[4] = (short)f2bf(f1[0]); v[5] = (short)f2bf(f1[1]);
  v[6] = (short)f2bf(f1[2]); v[7] = (short)f2bf(f1[3]);
  return v;
}
// async 16B global -> LDS (lane-linear dest: wave base + lane*16)
__device__ __forceinline__ void async_load16(const void* g, void* l) {
  __builtin_amdgcn_global_load_lds(
      (const __attribute__((address_space(1))) unsigned int*)g,
      (__attribute__((address_space(3))) unsigned int*)l, 16, 0, 0);
}

// ---------------------------------------------------------------------------
// Setup 1: build Bfull [L][4096][1280] bf16 from Whh fp32 + Wih fp32.
// Rows: [0,2048) = r,u: [Whh | Wihz]; [2048,3072) = hn: Whh only (k<1024);
// [3072,4096) = xn: Wihz only (k>=1024). Structural zeros never written
// (GEMM skips those kt ranges).
// ---------------------------------------------------------------------------
#define UL_R1 327680   // 2048*160
#define UL_R2 131072   // 1024*128
#define UL_R3 32768    // 1024*32
#define UL_   491520   // per-layer short8 units

__global__ __launch_bounds__(256) void cast_bfull_kernel(
    const float* __restrict__ Whh, const float* __restrict__ Wih,
    unsigned short* __restrict__ Bfull) {
  long u = (long)blockIdx.x * 256 + threadIdx.x;
  int l = (int)(u / UL_);
  int u2 = (int)(u % UL_);
  int j, slot;       // row in [0,4096), k-group slot in [0,160)
  if (u2 < UL_R1) { j = u2 / 160; slot = u2 % 160; }
  else if (u2 < UL_R1 + UL_R2) { int t = u2 - UL_R1; j = 2048 + t / 128; slot = t % 128; }
  else { int t = u2 - UL_R1 - UL_R2; j = 3072 + t / 32; slot = 128 + (t % 32); }
  int k0 = slot * 8;
  short8 v;
  if (k0 < 1024) {
    const float* src = Whh + ((size_t)l * THD_ + j) * HD_ + k0;
    v = pack8(*reinterpret_cast<const f32x4*>(src),
              *reinterpret_cast<const f32x4*>(src + 4));
  } else {
    int jw = (j >= 3072) ? (j - 1024) : j;     // xn rows map to Wih rows 2048..3071
    const float* src = Wih + ((size_t)l * THD_ + jw) * 257 + (k0 - 1024);
#pragma unroll
    for (int i = 0; i < 8; ++i) v[i] = (short)f2bf(src[i]);
  }
  *reinterpret_cast<short8*>(Bfull + (((size_t)l * NB_ + j) * 160 + slot) * 8) = v;
}

// ---------------------------------------------------------------------------
// Setup 2: cast pW1 / pW2 (padded to 128 rows) / recW to bf16.
// ---------------------------------------------------------------------------
#define U_PW1 4194304   // 32*1024*1024/8
#define U_PW2 262144    // 32*64*1024/8
#define U_REC 131072    // 1024*1024/8

__global__ __launch_bounds__(256) void cast_small_kernel(
    const float* __restrict__ pW1, const float* __restrict__ pW2,
    const float* __restrict__ recW,
    unsigned short* __restrict__ pW1b, unsigned short* __restrict__ pW2b,
    unsigned short* __restrict__ recWb) {
  long u = (long)blockIdx.x * 256 + threadIdx.x;
  const float* src;
  unsigned short* dst;
  if (u < U_PW1) { src = pW1 + u * 8; dst = pW1b + u * 8; }
  else if (u < U_PW1 + U_PW2) {
    long t = u - U_PW1;
    int l = (int)(t / 8192), r = (int)((t % 8192) / 128), kg = (int)(t % 128);
    src = pW2 + (((size_t)l * NW_ + r) * HD_ + kg * 8);
    dst = pW2b + (((size_t)l * 128 + r) * HD_ + kg * 8);
  } else {
    long t = u - U_PW1 - U_PW2;
    src = recW + t * 8; dst = recWb + t * 8;
  }
  *reinterpret_cast<short8*>(dst) =
      pack8(*reinterpret_cast<const f32x4*>(src),
            *reinterpret_cast<const f32x4*>(src + 4));
}

// ---------------------------------------------------------------------------
// Setup 3: A slabs (h=0 || z bf16), h32 zero, gate-constant table
// gateC[L][7][HD]: wtr, wtu, wtn, br(=bih+bhh), bu, bxn, bhn
// ---------------------------------------------------------------------------
__global__ __launch_bounds__(256) void init_misc_kernel(
    const float* __restrict__ z, const float* __restrict__ Wih,
    const float* __restrict__ bih, const float* __restrict__ bhh,
    unsigned short* __restrict__ Abuf, float* __restrict__ h32,
    float* __restrict__ gateC) {
  long idx = (long)blockIdx.x * 256 + threadIdx.x;
  const long N1 = (long)B_ * KA_;            // 1,310,720
  const long N2 = (long)L_ * 7 * HD_;        // 229,376
  if (idx < N1) {
    int b = (int)(idx / KA_), c = (int)(idx % KA_);
    unsigned short v = 0;
    if (c >= HD_) v = f2bf(z[(size_t)b * ZD_ + (c - HD_)]);
    Abuf[idx] = v;
    Abuf[N1 + idx] = v;
    if (c < HD_) h32[(size_t)b * HD_ + c] = 0.f;
  } else if (idx < N1 + N2) {
    long i2 = idx - N1;
    int n = (int)(i2 & 1023);
    int row = (int)(i2 >> 10);
    int l = row / 7, rr = row % 7;
    size_t g3 = (size_t)l * THD_;
    float v;
    if (rr == 0) v = Wih[(g3 + n) * 257 + 256];
    else if (rr == 1) v = Wih[(g3 + 1024 + n) * 257 + 256];
    else if (rr == 2) v = Wih[(g3 + 2048 + n) * 257 + 256];
    else if (rr == 3) v = bih[g3 + n] + bhh[g3 + n];
    else if (rr == 4) v = bih[g3 + 1024 + n] + bhh[g3 + 1024 + n];
    else if (rr == 5) v = bih[g3 + 2048 + n];
    else v = bhh[g3 + 2048 + n];
    gateC[((size_t)l * 7 + rr) * HD_ + n] = v;
  }
}

// ---------------------------------------------------------------------------
// bf16 x bf16 GEMM, 128x128 tile, BK=64, global_load_lds staging with XOR
// k-group swizzle, single-buffer 2-barrier K-loop. Used for MLP/recon tail.
// EPI: 0 = +bias, relu -> bf16 out; 1 = +bias, sigmoid -> f32;
//      2 = +bias, sigmoid -> f32 transposed [NW,B,L] (guard n<64)
// ---------------------------------------------------------------------------
template <int EPI>
__global__ __launch_bounds__(256) void gemm_bb_kernel(
    const unsigned short* __restrict__ Abase, long strideA, int lda,
    const unsigned short* __restrict__ Bbase, long strideB, int ldb,
    const float* __restrict__ biasBase, int strideBias,
    float* __restrict__ outBase, long strideOut, int ldo, int K64) {
  __shared__ __align__(16) unsigned short ldsA[128 * 64];   // [r][slot][8]
  __shared__ __align__(16) unsigned short ldsB[128 * 64];
  const int tid = threadIdx.x, lane = tid & 63, w = tid >> 6;
  const int wm = w & 1, wn = w >> 1;
  const int nb = blockIdx.x * 128, mb = blockIdx.y * 128;
  const int lz = blockIdx.z;
  const unsigned short* A = Abase + (long)lz * strideA;
  const unsigned short* Bw = Bbase + (long)lz * strideB;

  f32x4 zf = {0.f, 0.f, 0.f, 0.f};
  f32x4 acc[4][4];
#pragma unroll
  for (int i = 0; i < 4; ++i)
#pragma unroll
    for (int j = 0; j < 4; ++j) acc[i][j] = zf;

  // staging indices: unit i = tid + j*256 covers (r = i>>3, slot g = i&7)
  const int sr = tid >> 3, sg = tid & 7;
  const int q = lane >> 4, cc = lane & 15;

  for (int kt = 0; kt < K64; ++kt) {
    const int k0 = kt * 64;
#pragma unroll
    for (int j = 0; j < 4; ++j) {
      int r = sr + j * 32;
      int gg = sg ^ (r & 7);                      // global k-group for this slot
      async_load16(A + (size_t)(mb + r) * lda + k0 + gg * 8,
                   &ldsA[(size_t)(tid + j * 256) * 8]);
    }
#pragma unroll
    for (int j = 0; j < 4; ++j) {
      int r = sr + j * 32;
      int gg = sg ^ (r & 7);
      async_load16(Bw + (size_t)(nb + r) * ldb + k0 + gg * 8,
                   &ldsB[(size_t)(tid + j * 256) * 8]);
    }
    __syncthreads();
#pragma unroll
    for (int ks = 0; ks < 2; ++ks) {
      const int kq = ks * 4 + q;
      short8 a[4], b[4];
#pragma unroll
      for (int i = 0; i < 4; ++i) {
        int r = wm * 64 + i * 16 + cc;
        a[i] = *(const short8*)&ldsA[(size_t)(r * 8 + (kq ^ (r & 7))) * 8];
      }
#pragma unroll
      for (int j = 0; j < 4; ++j) {
        int n = wn * 64 + j * 16 + cc;
        b[j] = *(const short8*)&ldsB[(size_t)(n * 8 + (kq ^ (n & 7))) * 8];
      }
#pragma unroll
      for (int i = 0; i < 4; ++i)
#pragma unroll
        for (int j = 0; j < 4; ++j) acc[i][j] = mfma16(a[i], b[j], acc[i][j]);
    }
    __syncthreads();
  }

#pragma unroll
  for (int j = 0; j < 4; ++j) {
    int n = nb + wn * 64 + j * 16 + cc;
    float bv = 0.f;
    if constexpr (EPI == 0 || EPI == 1) bv = biasBase[(size_t)lz * strideBias + n];
    if constexpr (EPI == 2) bv = (n < NW_) ? biasBase[(size_t)lz * strideBias + n] : 0.f;
#pragma unroll
    for (int i = 0; i < 4; ++i) {
#pragma unroll
      for (int r = 0; r < 4; ++r) {
        int m = mb + wm * 64 + i * 16 + q * 4 + r;
        float v = acc[i][j][r] + bv;
        if constexpr (EPI == 0) {
          v = fmaxf(v, 0.f);
          reinterpret_cast<unsigned short*>(outBase)[(size_t)lz * strideOut + (size_t)m * ldo + n] = f2bf(v);
        } else if constexpr (EPI == 1) {
          outBase[(size_t)m * ldo + n] = sig_(v);
        } else if constexpr (EPI == 2) {
          if (n < NW_) outBase[((size_t)n * B_ + m) * L_ + lz] = sig_(v);
        }
      }
    }
  }
}

// ---------------------------------------------------------------------------
// Fused GRU step: gate-interleaved GEMM + elementwise epilogue.
// Block tile: 128 m-rows x 32 n-cols x 4 gates. B rows gathered from the 4
// gate regions of Bfull: tile row r -> gate g=(r>>4)&3, n = nb + (r>>6)*16
// + (r&15). hn (g=2) staged/computed only for kt<16, xn (g=3) only kt>=16:
// uniform 20-kt critical path, zero wasted FLOPs. 2-phase LDS double-buffer
// (stage kt+1 while computing kt, ONE barrier per kt) hides the vmcnt drain
// that dominates at 1 block/CU. Wave (wm,wn) holds all 4 gates for its
// (m,n) patch in acc[i][gate] -> GRU update entirely in-register, P buffer
// and gru_epi kernel eliminated.
// ---------------------------------------------------------------------------
__global__ __launch_bounds__(256) void gru_fused_kernel(
    const unsigned short* __restrict__ A,      // [B][KA] current slab
    const unsigned short* __restrict__ Bf,     // layer base [4096][1280]
    const float* __restrict__ gl,              // layer gateC [7][1024]
    const float* __restrict__ tcol,            // tmat [B][L]
    const float* __restrict__ eps_l,           // layer eps [B][HD]
    float* __restrict__ h32,
    unsigned short* __restrict__ Anext,
    unsigned short* __restrict__ hist_l,
    int l) {
  __shared__ __align__(16) unsigned short ldsA[2][128 * 64];
  __shared__ __align__(16) unsigned short ldsB[2][128 * 64];
  const int tid = threadIdx.x, lane = tid & 63, w = tid >> 6;
  const int wm = w & 1, wn = w >> 1;
  const int nb = blockIdx.x * 32;              // 32 n-columns per block
  const int mb = blockIdx.y * 128;
  const int sr = tid >> 3, sg = tid & 7;
  const int q = lane >> 4, cc = lane & 15;

  f32x4 zf = {0.f, 0.f, 0.f, 0.f};
  f32x4 acc[4][4];                             // [m-frag][gate]
#pragma unroll
  for (int i = 0; i < 4; ++i)
#pragma unroll
    for (int j = 0; j < 4; ++j) acc[i][j] = zf;

  auto stage = [&](int buf, int kt) {
    const int k0 = kt * 64;
#pragma unroll
    for (int j = 0; j < 4; ++j) {
      int r = sr + j * 32;
      int gg = sg ^ (r & 7);
      async_load16(A + (size_t)(mb + r) * KA_ + k0 + gg * 8,
                   &ldsA[buf][(size_t)(tid + j * 256) * 8]);
    }
    const int g3 = (kt < 16) ? 2 : 3;          // active third gate
#pragma unroll
    for (int j = 0; j < 4; ++j) {
      int r = sr + j * 32;
      int g = (r >> 4) & 3;
      if (g < 2 || g == g3) {
        int gg = sg ^ (r & 7);
        int grow = g * 1024 + nb + ((r >> 6) << 4) + (r & 15);
        async_load16(Bf + (size_t)grow * KA_ + k0 + gg * 8,
                     &ldsB[buf][(size_t)(tid + j * 256) * 8]);
      }
    }
  };

  stage(0, 0);
  __syncthreads();                             // vmcnt(0) drain + barrier
  int buf = 0;
#pragma unroll 1
  for (int kt = 0; kt < 20; ++kt) {
    if (kt < 19) stage(buf ^ 1, kt + 1);       // issue next tile early
    const bool lo = (kt < 16);
#pragma unroll
    for (int ks = 0; ks < 2; ++ks) {
      const int kq = ks * 4 + q;
      short8 a[4];
#pragma unroll
      for (int i = 0; i < 4; ++i) {
        int r = wm * 64 + i * 16 + cc;
        a[i] = *(const short8*)&ldsA[buf][(size_t)(r * 8 + (kq ^ (r & 7))) * 8];
      }
      int r0 = wn * 64 + cc;
      short8 b0 = *(const short8*)&ldsB[buf][(size_t)(r0 * 8 + (kq ^ (r0 & 7))) * 8];
      int r1 = wn * 64 + 16 + cc;
      short8 b1 = *(const short8*)&ldsB[buf][(size_t)(r1 * 8 + (kq ^ (r1 & 7))) * 8];
      int r3 = wn * 64 + (lo ? 32 : 48) + cc;
      short8 b3 = *(const short8*)&ldsB[buf][(size_t)(r3 * 8 + (kq ^ (r3 & 7))) * 8];
#pragma unroll
      for (int i = 0; i < 4; ++i) acc[i][0] = mfma16(a[i], b0, acc[i][0]);
#pragma unroll
      for (int i = 0; i < 4; ++i) acc[i][1] = mfma16(a[i], b1, acc[i][1]);
      if (lo) {
#pragma unroll
        for (int i = 0; i < 4; ++i) acc[i][2] = mfma16(a[i], b3, acc[i][2]);
      } else {
#pragma unroll
        for (int i = 0; i < 4; ++i) acc[i][3] = mfma16(a[i], b3, acc[i][3]);
      }
    }
    __syncthreads();                           // drains stage(buf^1), frees buf
    buf ^= 1;
  }

  // GRU elementwise epilogue, all gates in-register.
  const int n = nb + wn * 16 + cc;
  const float wtr = gl[n], wtu = gl[1024 + n], wtn = gl[2048 + n];
  const float br = gl[3072 + n], bu = gl[4096 + n];
  const float bxn = gl[5120 + n], bhn = gl[6144 + n];
  const float std_ = 1.0025031f;               // exp(0.5*0.005)
#pragma unroll
  for (int i = 0; i < 4; ++i) {
#pragma unroll
    for (int r = 0; r < 4; ++r) {
      int m = mb + wm * 64 + i * 16 + q * 4 + r;
      float tb = tcol[(size_t)m * L_ + l];
      float pr = acc[i][0][r], pu = acc[i][1][r];
      float ph = acc[i][2][r], px = acc[i][3][r];
      float rv = sig_(pr + tb * wtr + br);
      float uv = sig_(pu + tb * wtu + bu);
      float nv = tanh_(px + tb * wtn + bxn + rv * (ph + bhn));
      size_t ho = (size_t)m * HD_ + n;
      float hnew = (1.0f - uv) * nv + uv * h32[ho] + std_ * eps_l[ho];
      h32[ho] = hnew;
      unsigned short hb = f2bf(hnew);
      Anext[(size_t)m * KA_ + n] = hb;
      hist_l[ho] = hb;
    }
  }
}

// ---------------------------------------------------------------------------
extern "C" void kernel_launch(void* const* d_in, const int* in_sizes, int n_in,
                              void* d_out, int out_size, void* d_ws, size_t ws_size,
                              hipStream_t stream) {
  const float* z    = (const float*)d_in[0];
  const float* tmat = (const float*)d_in[1];
  const float* eps  = (const float*)d_in[2];
  const float* Wih  = (const float*)d_in[3];
  const float* Whh  = (const float*)d_in[4];
  const float* bih  = (const float*)d_in[5];
  const float* bhh  = (const float*)d_in[6];
  const float* pW1  = (const float*)d_in[7];
  const float* pb1  = (const float*)d_in[8];
  const float* pW2  = (const float*)d_in[9];
  const float* pb2  = (const float*)d_in[10];
  const float* recW = (const float*)d_in[11];
  const float* recb = (const float*)d_in[12];
  float* out = (float*)d_out;

  char* ws = (char*)d_ws;
  unsigned short* Abuf  = (unsigned short*)(ws);               // 5,242,880
  float*          h32   = (float*)(ws + 5242880);              // 4,194,304
  unsigned short* hist  = (unsigned short*)(ws + 9437184);     // 67,108,864
  unsigned short* act   = (unsigned short*)(ws + 76546048);    // 67,108,864
  // (ws + 143654912): former P buffer, 16,777,216 — now unused
  float*          gateC = (float*)(ws + 160432128);            // 917,504
  unsigned short* Bfull = (unsigned short*)(ws + 161349632);   // 335,544,320
  unsigned short* pW1b  = (unsigned short*)(ws + 496893952);   // 67,108,864
  unsigned short* pW2b  = (unsigned short*)(ws + 564002816);   // 8,388,608
  unsigned short* recWb = (unsigned short*)(ws + 572391424);   // 2,097,152
  // total: 574,488,576 bytes

  cast_bfull_kernel<<<61440, 256, 0, stream>>>(Whh, Wih, Bfull);
  cast_small_kernel<<<17920, 256, 0, stream>>>(pW1, pW2, recW, pW1b, pW2b, recWb);
  {
    long total = (long)B_ * KA_ + (long)L_ * 7 * HD_;
    init_misc_kernel<<<(int)((total + 255) / 256), 256, 0, stream>>>(
        z, Wih, bih, bhh, Abuf, h32, gateC);
  }
  for (int l = 0; l < L_; ++l) {
    const unsigned short* Acur = Abuf + (size_t)(l & 1) * B_ * KA_;
    unsigned short* Anext      = Abuf + (size_t)((l + 1) & 1) * B_ * KA_;
    gru_fused_kernel<<<dim3(32, 8), 256, 0, stream>>>(
        Acur, Bfull + (size_t)l * NB_ * KA_, gateC + (size_t)l * 7 * HD_,
        tmat, eps + (size_t)l * B_ * HD_, h32, Anext,
        hist + (size_t)l * B_ * HD_, l);
  }
  // MLP layer 1: act = relu(hist @ W1^T + b1) -> bf16, batched over L
  gemm_bb_kernel<0><<<dim3(8, 8, L_), 256, 0, stream>>>(
      hist, (long)B_ * HD_, HD_, pW1b, (long)HD_ * HD_, HD_, pb1, HD_,
      (float*)act, (long)B_ * HD_, HD_, 16);
  // MLP layer 2: preds -> transposed [NW, B, L] region of d_out
  gemm_bb_kernel<2><<<dim3(1, 8, L_), 256, 0, stream>>>(
      act, (long)B_ * HD_, HD_, pW2b, (long)128 * HD_, HD_, pb2, NW_,
      out + (size_t)B_ * XD_, 0, 0, 16);
  // recon = sigmoid(h_T @ recW^T + recb)
  gemm_bb_kernel<1><<<dim3(8, 8, 1), 256, 0, stream>>>(
      hist + (size_t)(L_ - 1) * B_ * HD_, 0, HD_, recWb, 0, HD_, recb, 0,
      out, 0, XD_, 16);
}

// Round 2
// 1882.021 us; speedup vs baseline: 1.0849x; 1.0849x over previous
//
#include <hip/hip_runtime.h>
#include <hip/hip_bf16.h>
#include <math.h>

#define B_   1024
#define ZD_  256
#define HD_  1024
#define L_   32
#define NW_  64
#define XD_  1024
#define KA_  1280   // concat K: 1024 (h) + 256 (z)
#define THD_ 3072
#define NB_  4096   // augmented N: r, u, hn, xn

typedef __attribute__((ext_vector_type(8))) short short8;
typedef __attribute__((ext_vector_type(4))) float f32x4;

__device__ __forceinline__ unsigned short f2bf(float f) {
  unsigned int u = __float_as_uint(f);
  u += 0x7fffu + ((u >> 16) & 1u);   // RNE
  return (unsigned short)(u >> 16);
}
__device__ __forceinline__ float sig_(float x) { return 1.0f / (1.0f + __expf(-x)); }
__device__ __forceinline__ float tanh_(float x) {
  float e = __expf(2.0f * x);
  return 1.0f - 2.0f / (e + 1.0f);
}
__device__ __forceinline__ f32x4 mfma16(short8 a, short8 b, f32x4 c) {
  return __builtin_amdgcn_mfma_f32_16x16x32_bf16(a, b, c, 0, 0, 0);
}
__device__ __forceinline__ short8 pack8(f32x4 f0, f32x4 f1) {
  short8 v;
  v[0] = (short)f2bf(f0[0]); v[1] = (short)f2bf(f0[1]);
  v[2] = (short)f2bf(f0[2]); v[3] = (short)f2bf(f0[3]);
  v[4] = (short)f2bf(f1[0]); v[5] = (short)f2bf(f1[1]);
  v[6] = (short)f2bf(f1[2]); v[7] = (short)f2bf(f1[3]);
  return v;
}
// async 16B global -> LDS (lane-linear dest: wave base + lane*16)
__device__ __forceinline__ void async_load16(const void* g, void* l) {
  __builtin_amdgcn_global_load_lds(
      (const __attribute__((address_space(1))) unsigned int*)g,
      (__attribute__((address_space(3))) unsigned int*)l, 16, 0, 0);
}

// ---------------------------------------------------------------------------
// Setup 1: build Bfull [L][4096][1280] bf16 from Whh fp32 + Wih fp32.
// Rows: [0,2048) = r,u: [Whh | Wihz]; [2048,3072) = hn: Whh only (k<1024);
// [3072,4096) = xn: Wihz only (k>=1024). Structural zeros never written
// (GEMM skips those kt ranges).
// ---------------------------------------------------------------------------
#define UL_R1 327680   // 2048*160
#define UL_R2 131072   // 1024*128
#define UL_R3 32768    // 1024*32
#define UL_   491520   // per-layer short8 units

__global__ __launch_bounds__(256) void cast_bfull_kernel(
    const float* __restrict__ Whh, const float* __restrict__ Wih,
    unsigned short* __restrict__ Bfull) {
  long u = (long)blockIdx.x * 256 + threadIdx.x;
  int l = (int)(u / UL_);
  int u2 = (int)(u % UL_);
  int j, slot;       // row in [0,4096), k-group slot in [0,160)
  if (u2 < UL_R1) { j = u2 / 160; slot = u2 % 160; }
  else if (u2 < UL_R1 + UL_R2) { int t = u2 - UL_R1; j = 2048 + t / 128; slot = t % 128; }
  else { int t = u2 - UL_R1 - UL_R2; j = 3072 + t / 32; slot = 128 + (t % 32); }
  int k0 = slot * 8;
  short8 v;
  if (k0 < 1024) {
    const float* src = Whh + ((size_t)l * THD_ + j) * HD_ + k0;
    v = pack8(*reinterpret_cast<const f32x4*>(src),
              *reinterpret_cast<const f32x4*>(src + 4));
  } else {
    int jw = (j >= 3072) ? (j - 1024) : j;     // xn rows map to Wih rows 2048..3071
    const float* src = Wih + ((size_t)l * THD_ + jw) * 257 + (k0 - 1024);
#pragma unroll
    for (int i = 0; i < 8; ++i) v[i] = (short)f2bf(src[i]);
  }
  *reinterpret_cast<short8*>(Bfull + (((size_t)l * NB_ + j) * 160 + slot) * 8) = v;
}

// ---------------------------------------------------------------------------
// Setup 2: cast pW1 / pW2 (padded to 128 rows) / recW to bf16.
// ---------------------------------------------------------------------------
#define U_PW1 4194304   // 32*1024*1024/8
#define U_PW2 262144    // 32*64*1024/8
#define U_REC 131072    // 1024*1024/8

__global__ __launch_bounds__(256) void cast_small_kernel(
    const float* __restrict__ pW1, const float* __restrict__ pW2,
    const float* __restrict__ recW,
    unsigned short* __restrict__ pW1b, unsigned short* __restrict__ pW2b,
    unsigned short* __restrict__ recWb) {
  long u = (long)blockIdx.x * 256 + threadIdx.x;
  const float* src;
  unsigned short* dst;
  if (u < U_PW1) { src = pW1 + u * 8; dst = pW1b + u * 8; }
  else if (u < U_PW1 + U_PW2) {
    long t = u - U_PW1;
    int l = (int)(t / 8192), r = (int)((t % 8192) / 128), kg = (int)(t % 128);
    src = pW2 + (((size_t)l * NW_ + r) * HD_ + kg * 8);
    dst = pW2b + (((size_t)l * 128 + r) * HD_ + kg * 8);
  } else {
    long t = u - U_PW1 - U_PW2;
    src = recW + t * 8; dst = recWb + t * 8;
  }
  *reinterpret_cast<short8*>(dst) =
      pack8(*reinterpret_cast<const f32x4*>(src),
            *reinterpret_cast<const f32x4*>(src + 4));
}

// ---------------------------------------------------------------------------
// Setup 3: A slabs (h=0 || z bf16), h32 zero, gate-constant table
// gateC[L][7][HD]: wtr, wtu, wtn, br(=bih+bhh), bu, bxn, bhn
// ---------------------------------------------------------------------------
__global__ __launch_bounds__(256) void init_misc_kernel(
    const float* __restrict__ z, const float* __restrict__ Wih,
    const float* __restrict__ bih, const float* __restrict__ bhh,
    unsigned short* __restrict__ Abuf, float* __restrict__ h32,
    float* __restrict__ gateC) {
  long idx = (long)blockIdx.x * 256 + threadIdx.x;
  const long N1 = (long)B_ * KA_;            // 1,310,720
  const long N2 = (long)L_ * 7 * HD_;        // 229,376
  if (idx < N1) {
    int b = (int)(idx / KA_), c = (int)(idx % KA_);
    unsigned short v = 0;
    if (c >= HD_) v = f2bf(z[(size_t)b * ZD_ + (c - HD_)]);
    Abuf[idx] = v;
    Abuf[N1 + idx] = v;
    if (c < HD_) h32[(size_t)b * HD_ + c] = 0.f;
  } else if (idx < N1 + N2) {
    long i2 = idx - N1;
    int n = (int)(i2 & 1023);
    int row = (int)(i2 >> 10);
    int l = row / 7, rr = row % 7;
    size_t g3 = (size_t)l * THD_;
    float v;
    if (rr == 0) v = Wih[(g3 + n) * 257 + 256];
    else if (rr == 1) v = Wih[(g3 + 1024 + n) * 257 + 256];
    else if (rr == 2) v = Wih[(g3 + 2048 + n) * 257 + 256];
    else if (rr == 3) v = bih[g3 + n] + bhh[g3 + n];
    else if (rr == 4) v = bih[g3 + 1024 + n] + bhh[g3 + 1024 + n];
    else if (rr == 5) v = bih[g3 + 2048 + n];
    else v = bhh[g3 + 2048 + n];
    gateC[((size_t)l * 7 + rr) * HD_ + n] = v;
  }
}

// ---------------------------------------------------------------------------
// bf16 x bf16 GEMM, 128x128 tile, BK=64, global_load_lds staging with XOR
// k-group swizzle, single-buffer 2-barrier K-loop. Used for MLP/recon tail.
// EPI: 0 = +bias, relu -> bf16 out; 1 = +bias, sigmoid -> f32;
//      2 = +bias, sigmoid -> f32 transposed [NW,B,L] (guard n<64)
// ---------------------------------------------------------------------------
template <int EPI>
__global__ __launch_bounds__(256) void gemm_bb_kernel(
    const unsigned short* __restrict__ Abase, long strideA, int lda,
    const unsigned short* __restrict__ Bbase, long strideB, int ldb,
    const float* __restrict__ biasBase, int strideBias,
    float* __restrict__ outBase, long strideOut, int ldo, int K64) {
  __shared__ __align__(16) unsigned short ldsA[128 * 64];   // [r][slot][8]
  __shared__ __align__(16) unsigned short ldsB[128 * 64];
  const int tid = threadIdx.x, lane = tid & 63, w = tid >> 6;
  const int wm = w & 1, wn = w >> 1;
  const int nb = blockIdx.x * 128, mb = blockIdx.y * 128;
  const int lz = blockIdx.z;
  const unsigned short* A = Abase + (long)lz * strideA;
  const unsigned short* Bw = Bbase + (long)lz * strideB;

  f32x4 zf = {0.f, 0.f, 0.f, 0.f};
  f32x4 acc[4][4];
#pragma unroll
  for (int i = 0; i < 4; ++i)
#pragma unroll
    for (int j = 0; j < 4; ++j) acc[i][j] = zf;

  // staging indices: unit i = tid + j*256 covers (r = i>>3, slot g = i&7)
  const int sr = tid >> 3, sg = tid & 7;
  const int q = lane >> 4, cc = lane & 15;

  for (int kt = 0; kt < K64; ++kt) {
    const int k0 = kt * 64;
#pragma unroll
    for (int j = 0; j < 4; ++j) {
      int r = sr + j * 32;
      int gg = sg ^ (r & 7);                      // global k-group for this slot
      async_load16(A + (size_t)(mb + r) * lda + k0 + gg * 8,
                   &ldsA[(size_t)(tid + j * 256) * 8]);
    }
#pragma unroll
    for (int j = 0; j < 4; ++j) {
      int r = sr + j * 32;
      int gg = sg ^ (r & 7);
      async_load16(Bw + (size_t)(nb + r) * ldb + k0 + gg * 8,
                   &ldsB[(size_t)(tid + j * 256) * 8]);
    }
    __syncthreads();
#pragma unroll
    for (int ks = 0; ks < 2; ++ks) {
      const int kq = ks * 4 + q;
      short8 a[4], b[4];
#pragma unroll
      for (int i = 0; i < 4; ++i) {
        int r = wm * 64 + i * 16 + cc;
        a[i] = *(const short8*)&ldsA[(size_t)(r * 8 + (kq ^ (r & 7))) * 8];
      }
#pragma unroll
      for (int j = 0; j < 4; ++j) {
        int n = wn * 64 + j * 16 + cc;
        b[j] = *(const short8*)&ldsB[(size_t)(n * 8 + (kq ^ (n & 7))) * 8];
      }
#pragma unroll
      for (int i = 0; i < 4; ++i)
#pragma unroll
        for (int j = 0; j < 4; ++j) acc[i][j] = mfma16(a[i], b[j], acc[i][j]);
    }
    __syncthreads();
  }

#pragma unroll
  for (int j = 0; j < 4; ++j) {
    int n = nb + wn * 64 + j * 16 + cc;
    float bv = 0.f;
    if constexpr (EPI == 0 || EPI == 1) bv = biasBase[(size_t)lz * strideBias + n];
    if constexpr (EPI == 2) bv = (n < NW_) ? biasBase[(size_t)lz * strideBias + n] : 0.f;
#pragma unroll
    for (int i = 0; i < 4; ++i) {
#pragma unroll
      for (int r = 0; r < 4; ++r) {
        int m = mb + wm * 64 + i * 16 + q * 4 + r;
        float v = acc[i][j][r] + bv;
        if constexpr (EPI == 0) {
          v = fmaxf(v, 0.f);
          reinterpret_cast<unsigned short*>(outBase)[(size_t)lz * strideOut + (size_t)m * ldo + n] = f2bf(v);
        } else if constexpr (EPI == 1) {
          outBase[(size_t)m * ldo + n] = sig_(v);
        } else if constexpr (EPI == 2) {
          if (n < NW_) outBase[((size_t)n * B_ + m) * L_ + lz] = sig_(v);
        }
      }
    }
  }
}

// ---------------------------------------------------------------------------
// Fused GRU step: gate-interleaved GEMM + elementwise epilogue.
// R1 retile: block = 128 m-rows x 16 n-cols x 4 gates -> grid 64x8 = 512
// blocks = 2 blocks/CU (was 1), LDS 48 KB/block (A 2x16KB + B 2x8KB).
// With 1 block/CU the __syncthreads vmcnt(0) drain stalled every kt (no TLP
// to hide ~residual L3 latency over the ~300cy compute phase); 2 blocks/CU
// lets one block's drain overlap the other's MFMA phase. B tile rows 0..63:
// gate g = r>>4, n = nb + (r&15); hn (g=2) staged/computed only kt<16, xn
// (g=3) only kt>=16. Wave w owns m-rows [w*32, w*32+32) x all 16 n-cols,
// acc[2][4] (32 VGPRs). GRU update entirely in-register.
// ---------------------------------------------------------------------------
__global__ __launch_bounds__(256) void gru_fused_kernel(
    const unsigned short* __restrict__ A,      // [B][KA] current slab
    const unsigned short* __restrict__ Bf,     // layer base [4096][1280]
    const float* __restrict__ gl,              // layer gateC [7][1024]
    const float* __restrict__ tcol,            // tmat [B][L]
    const float* __restrict__ eps_l,           // layer eps [B][HD]
    float* __restrict__ h32,
    unsigned short* __restrict__ Anext,
    unsigned short* __restrict__ hist_l,
    int l) {
  __shared__ __align__(16) unsigned short ldsA[2][128 * 64];
  __shared__ __align__(16) unsigned short ldsB[2][64 * 64];
  const int tid = threadIdx.x, lane = tid & 63, w = tid >> 6;
  const int nb = blockIdx.x * 16;              // 16 n-columns per block
  const int mb = blockIdx.y * 128;
  const int sr = tid >> 3, sg = tid & 7;
  const int q = lane >> 4, cc = lane & 15;

  f32x4 zf = {0.f, 0.f, 0.f, 0.f};
  f32x4 acc[2][4];                             // [m-frag][gate]
#pragma unroll
  for (int i = 0; i < 2; ++i)
#pragma unroll
    for (int j = 0; j < 4; ++j) acc[i][j] = zf;

  auto stage = [&](int buf, int kt) {
    const int k0 = kt * 64;
#pragma unroll
    for (int j = 0; j < 4; ++j) {
      int r = sr + j * 32;
      int gg = sg ^ (r & 7);
      async_load16(A + (size_t)(mb + r) * KA_ + k0 + gg * 8,
                   &ldsA[buf][(size_t)(tid + j * 256) * 8]);
    }
    const int g3 = (kt < 16) ? 2 : 3;          // active third gate
#pragma unroll
    for (int j = 0; j < 2; ++j) {
      int r = sr + j * 32;                     // 0..63
      int g = r >> 4;                          // gate for this tile row
      if (g < 2 || g == g3) {
        int gg = sg ^ (r & 7);
        int grow = g * 1024 + nb + (r & 15);
        async_load16(Bf + (size_t)grow * KA_ + k0 + gg * 8,
                     &ldsB[buf][(size_t)(tid + j * 256) * 8]);
      }
    }
  };

  stage(0, 0);
  __syncthreads();                             // vmcnt(0) drain + barrier
  int buf = 0;
#pragma unroll 1
  for (int kt = 0; kt < 20; ++kt) {
    if (kt < 19) stage(buf ^ 1, kt + 1);       // issue next tile early
    const bool lo = (kt < 16);
#pragma unroll
    for (int ks = 0; ks < 2; ++ks) {
      const int kq = ks * 4 + q;
      short8 a0, a1, b0, b1, b3;
      { int r = w * 32 + cc;
        a0 = *(const short8*)&ldsA[buf][(size_t)(r * 8 + (kq ^ (r & 7))) * 8]; }
      { int r = w * 32 + 16 + cc;
        a1 = *(const short8*)&ldsA[buf][(size_t)(r * 8 + (kq ^ (r & 7))) * 8]; }
      { int rb = cc;
        b0 = *(const short8*)&ldsB[buf][(size_t)(rb * 8 + (kq ^ (rb & 7))) * 8]; }
      { int rb = 16 + cc;
        b1 = *(const short8*)&ldsB[buf][(size_t)(rb * 8 + (kq ^ (rb & 7))) * 8]; }
      { int rb = (lo ? 32 : 48) + cc;
        b3 = *(const short8*)&ldsB[buf][(size_t)(rb * 8 + (kq ^ (rb & 7))) * 8]; }
      acc[0][0] = mfma16(a0, b0, acc[0][0]);
      acc[1][0] = mfma16(a1, b0, acc[1][0]);
      acc[0][1] = mfma16(a0, b1, acc[0][1]);
      acc[1][1] = mfma16(a1, b1, acc[1][1]);
      if (lo) {
        acc[0][2] = mfma16(a0, b3, acc[0][2]);
        acc[1][2] = mfma16(a1, b3, acc[1][2]);
      } else {
        acc[0][3] = mfma16(a0, b3, acc[0][3]);
        acc[1][3] = mfma16(a1, b3, acc[1][3]);
      }
    }
    __syncthreads();                           // drains stage(buf^1), frees buf
    buf ^= 1;
  }

  // GRU elementwise epilogue, all gates in-register.
  const int n = nb + cc;
  const float wtr = gl[n], wtu = gl[1024 + n], wtn = gl[2048 + n];
  const float br = gl[3072 + n], bu = gl[4096 + n];
  const float bxn = gl[5120 + n], bhn = gl[6144 + n];
  const float std_ = 1.0025031f;               // exp(0.5*0.005)
#pragma unroll
  for (int i = 0; i < 2; ++i) {
#pragma unroll
    for (int r = 0; r < 4; ++r) {
      int m = mb + w * 32 + i * 16 + q * 4 + r;
      float tb = tcol[(size_t)m * L_ + l];
      float pr = acc[i][0][r], pu = acc[i][1][r];
      float ph = acc[i][2][r], px = acc[i][3][r];
      float rv = sig_(pr + tb * wtr + br);
      float uv = sig_(pu + tb * wtu + bu);
      float nv = tanh_(px + tb * wtn + bxn + rv * (ph + bhn));
      size_t ho = (size_t)m * HD_ + n;
      float hnew = (1.0f - uv) * nv + uv * h32[ho] + std_ * eps_l[ho];
      h32[ho] = hnew;
      unsigned short hb = f2bf(hnew);
      Anext[(size_t)m * KA_ + n] = hb;
      hist_l[ho] = hb;
    }
  }
}

// ---------------------------------------------------------------------------
extern "C" void kernel_launch(void* const* d_in, const int* in_sizes, int n_in,
                              void* d_out, int out_size, void* d_ws, size_t ws_size,
                              hipStream_t stream) {
  const float* z    = (const float*)d_in[0];
  const float* tmat = (const float*)d_in[1];
  const float* eps  = (const float*)d_in[2];
  const float* Wih  = (const float*)d_in[3];
  const float* Whh  = (const float*)d_in[4];
  const float* bih  = (const float*)d_in[5];
  const float* bhh  = (const float*)d_in[6];
  const float* pW1  = (const float*)d_in[7];
  const float* pb1  = (const float*)d_in[8];
  const float* pW2  = (const float*)d_in[9];
  const float* pb2  = (const float*)d_in[10];
  const float* recW = (const float*)d_in[11];
  const float* recb = (const float*)d_in[12];
  float* out = (float*)d_out;

  char* ws = (char*)d_ws;
  unsigned short* Abuf  = (unsigned short*)(ws);               // 5,242,880
  float*          h32   = (float*)(ws + 5242880);              // 4,194,304
  unsigned short* hist  = (unsigned short*)(ws + 9437184);     // 67,108,864
  unsigned short* act   = (unsigned short*)(ws + 76546048);    // 67,108,864
  // (ws + 143654912): former P buffer, 16,777,216 — now unused
  float*          gateC = (float*)(ws + 160432128);            // 917,504
  unsigned short* Bfull = (unsigned short*)(ws + 161349632);   // 335,544,320
  unsigned short* pW1b  = (unsigned short*)(ws + 496893952);   // 67,108,864
  unsigned short* pW2b  = (unsigned short*)(ws + 564002816);   // 8,388,608
  unsigned short* recWb = (unsigned short*)(ws + 572391424);   // 2,097,152
  // total: 574,488,576 bytes

  cast_bfull_kernel<<<61440, 256, 0, stream>>>(Whh, Wih, Bfull);
  cast_small_kernel<<<17920, 256, 0, stream>>>(pW1, pW2, recW, pW1b, pW2b, recWb);
  {
    long total = (long)B_ * KA_ + (long)L_ * 7 * HD_;
    init_misc_kernel<<<(int)((total + 255) / 256), 256, 0, stream>>>(
        z, Wih, bih, bhh, Abuf, h32, gateC);
  }
  for (int l = 0; l < L_; ++l) {
    const unsigned short* Acur = Abuf + (size_t)(l & 1) * B_ * KA_;
    unsigned short* Anext      = Abuf + (size_t)((l + 1) & 1) * B_ * KA_;
    gru_fused_kernel<<<dim3(64, 8), 256, 0, stream>>>(
        Acur, Bfull + (size_t)l * NB_ * KA_, gateC + (size_t)l * 7 * HD_,
        tmat, eps + (size_t)l * B_ * HD_, h32, Anext,
        hist + (size_t)l * B_ * HD_, l);
  }
  // MLP layer 1: act = relu(hist @ W1^T + b1) -> bf16, batched over L
  gemm_bb_kernel<0><<<dim3(8, 8, L_), 256, 0, stream>>>(
      hist, (long)B_ * HD_, HD_, pW1b, (long)HD_ * HD_, HD_, pb1, HD_,
      (float*)act, (long)B_ * HD_, HD_, 16);
  // MLP layer 2: preds -> transposed [NW, B, L] region of d_out
  gemm_bb_kernel<2><<<dim3(1, 8, L_), 256, 0, stream>>>(
      act, (long)B_ * HD_, HD_, pW2b, (long)128 * HD_, HD_, pb2, NW_,
      out + (size_t)B_ * XD_, 0, 0, 16);
  // recon = sigmoid(h_T @ recW^T + recb)
  gemm_bb_kernel<1><<<dim3(8, 8, 1), 256, 0, stream>>>(
      hist + (size_t)(L_ - 1) * B_ * HD_, 0, HD_, recWb, 0, HD_, recb, 0,
      out, 0, XD_, 16);
}